// Round 7
// baseline (480.097 us; speedup 1.0000x reference)
//
#include <hip/hip_runtime.h>
#include <stdint.h>
#include <math.h>

// Problem constants (Phi3 attention block)
#define B_   2
#define S_   2048
#define H_   3072
#define NH   32
#define NKV  8
#define HD   96
#define OPSZ 4608          // NH*HD + 2*NKV*HD
#define MM   (B_*S_)       // 4096 token rows

typedef __attribute__((ext_vector_type(8))) short short8;
typedef __attribute__((ext_vector_type(4))) float floatx4;

__device__ __forceinline__ short f2bf(float f) {
    union { float f; uint32_t u; } v; v.f = f;
    uint32_t r = v.u + 0x7fffu + ((v.u >> 16) & 1u);   // RNE
    return (short)(r >> 16);
}
__device__ __forceinline__ float bf2f(short s) {
    union { uint32_t u; float f; } v; v.u = ((uint32_t)(uint16_t)s) << 16;
    return v.f;
}
// truncating bf16x2 pack (P in [0,1]; bias <= 2^-9 rel, numerator & denominator consistent)
__device__ __forceinline__ uint32_t pk_bf_trunc(float lo, float hi) {
    union { float f; uint32_t u; } a, b; a.f = lo; b.f = hi;
    return (a.u >> 16) | (b.u & 0xFFFF0000u);
}
// raw v_exp_f32 (base-2): skips OCML denorm-fixup tail; -3e38 input -> 0
__device__ __forceinline__ float fast_exp2(float x) {
    float r;
    asm volatile("v_exp_f32 %0, %1" : "=v"(r) : "v"(x));
    return r;
}
// max over the 16 lanes of a DPP row via row_ror rotate-reduce (pure VALU)
__device__ __forceinline__ float dpp_max16(float x) {
    union { float f; int i; } a, t;
    a.f = x;
    t.i = __builtin_amdgcn_update_dpp(0, a.i, 0x128, 0xF, 0xF, false); a.f = fmaxf(a.f, t.f);
    t.i = __builtin_amdgcn_update_dpp(0, a.i, 0x124, 0xF, 0xF, false); a.f = fmaxf(a.f, t.f);
    t.i = __builtin_amdgcn_update_dpp(0, a.i, 0x122, 0xF, 0xF, false); a.f = fmaxf(a.f, t.f);
    t.i = __builtin_amdgcn_update_dpp(0, a.i, 0x121, 0xF, 0xF, false); a.f = fmaxf(a.f, t.f);
    return a.f;
}

// async global->LDS, 16B per lane; lds dest is wave-uniform base + lane*16
__device__ __forceinline__ void async_load16(const void* g, void* l) {
    __builtin_amdgcn_global_load_lds(
        (const __attribute__((address_space(1))) void*)g,
        (__attribute__((address_space(3))) void*)l, 16, 0, 0);
}

// ---------------------------------------------------------------- merged casts fp32->bf16
#define CN1 (MM * H_ / 4)
#define CN2 (OPSZ * H_ / 4)
#define CN3 (H_ * H_ / 4)
__global__ void cast3_f32_bf16(const float* __restrict__ s1, const float* __restrict__ s2,
                               const float* __restrict__ s3, short* __restrict__ d1,
                               short* __restrict__ d2, short* __restrict__ d3) {
    int gid = blockIdx.x * blockDim.x + threadIdx.x;
    int stride = gridDim.x * blockDim.x;
    for (int i = gid; i < CN1; i += stride) {
        float4 v = ((const float4*)s1)[i];
        short4 o; o.x = f2bf(v.x); o.y = f2bf(v.y); o.z = f2bf(v.z); o.w = f2bf(v.w);
        ((short4*)d1)[i] = o;
    }
    for (int i = gid; i < CN2; i += stride) {
        float4 v = ((const float4*)s2)[i];
        short4 o; o.x = f2bf(v.x); o.y = f2bf(v.y); o.z = f2bf(v.z); o.w = f2bf(v.w);
        ((short4*)d2)[i] = o;
    }
    for (int i = gid; i < CN3; i += stride) {
        float4 v = ((const float4*)s3)[i];
        short4 o; o.x = f2bf(v.x); o.y = f2bf(v.y); o.z = f2bf(v.z); o.w = f2bf(v.w);
        ((short4*)d3)[i] = o;
    }
}

// ---------------------------------------------------------------- GEMM  C[M,N] = A[M,K] * B[N,K]^T
// v6: BM=256, BN templated (288 QKV / 192 WO), 256 blocks, st_16x32 swizzle,
// counted vmcnt, 2 barriers/K-tile -- identical macro-structure to the verified v4.
// K-loop micro-structure: NF single-fragment phases with a 3-SLOT B ring
// (prefetch frag g+1 into slot (g+1)%3 while MFMA consumes slot g%3).
//  - peak live B regs 72 -> 24 (v4's three live groups flirted with the 256-VGPR
//    ceiling at BN=288: acc 144 + a 32 + b 72 + addressing)
//  - WAR on a ring slot is vs MFMAs TWO phases back (retired) -- avoids round-5's
//    ping-pong serialization (write waited on the immediately preceding group)
//  - per-element accumulation order (kk0 then kk1 per K-tile) bit-identical to v4
//  - final phase's MFMA still runs after barrier+stage (same overlap as v4);
//    its B frag is ds_read BEFORE the barrier (ring slot filled in phase NF-2)
template<int BN, int OUT_BF16>
__global__ __launch_bounds__(512, 2) void gemmN(const short* __restrict__ A, const short* __restrict__ Bm,
                                                float* __restrict__ Cf, short* __restrict__ Cb,
                                                int M, int N, int K) {
    constexpr int NF    = BN / 32;        // n-frags per wave (9 | 6)
    constexpr int BSUB  = BN / 8;         // B subtiles (36 | 24)
    constexpr int BBY   = BN * 128;       // B bytes per buffer
    constexpr int JB    = (BSUB + 7) / 8; // B stage loads upper bound per wave (5 | 3)
    __shared__ __align__(16) char smem[65536 + 2 * BBY];
    const int tid = threadIdx.x;
    const int w = tid >> 6, l = tid & 63;
    const int L15 = l & 15, quad = l >> 4;
    const int wr = w & 3, wc = w >> 2;    // wave grid 4x2

    const int gm = M >> 8;                // 16
    const int nwg = gridDim.x;
    const int id = blockIdx.x;
    // bijective XCD remap (m204)
    const int qq = nwg >> 3, rr = nwg & 7;
    const int xcd = id & 7, sidx = id >> 3;
    const int wgid = (xcd < rr ? xcd * (qq + 1) : rr * (qq + 1) + (xcd - rr) * qq) + sidx;
    const int m0 = (wgid % gm) << 8;
    const int n0 = (wgid / gm) * BN;

    // staging source byte-offsets (inverse st_16x32 swizzle folded into the source)
    const int cbl = ((l & 3) * 16) ^ (((l >> 5) & 1) << 5);
    uint32_t aofs[4], bofs[JB];
    #pragma unroll
    for (int j = 0; j < 4; j++) {
        const int s = j * 8 + w;
        const int row = ((s >> 1) << 4) + (l >> 2);
        const int colb = ((s & 1) << 6) + cbl;
        aofs[j] = (uint32_t)(m0 + row) * (uint32_t)(K * 2) + colb;
    }
    #pragma unroll
    for (int j = 0; j < JB; j++) {
        const int s = j * 8 + w;
        const int sc = (s < BSUB) ? s : 0;             // clamp (unused when guarded)
        const int row = ((sc >> 1) << 4) + (l >> 2);
        const int colb = ((sc & 1) << 6) + cbl;
        bofs[j] = (uint32_t)(n0 + row) * (uint32_t)(K * 2) + colb;
    }
    char* ldsA = (char*)smem;
    char* ldsB = (char*)smem + 65536;

    // ds_read lane constant: phys = subtile_pair*2048 + kk*1024 + L15*64 + (quad*16 ^ (L15bit3<<5))
    const int lane_off = L15 * 64 + ((quad * 16) ^ (((L15 >> 3) & 1) << 5));
    const int aoff = (wr * 4) * 2048 + lane_off;       // + m*2048 + kk*1024
    const int boff = (wc * NF) * 2048 + lane_off;      // + n*2048 + kk*1024

    floatx4 acc[4][NF];
    #pragma unroll
    for (int i = 0; i < 4; i++)
        #pragma unroll
        for (int j = 0; j < NF; j++)
            acc[i][j] = (floatx4){0.f, 0.f, 0.f, 0.f};

    auto stageA = [&](int kt, int buf) {
        const uint32_t kb = (uint32_t)kt << 7;
        #pragma unroll
        for (int j = 0; j < 4; j++)
            async_load16((const char*)A + (size_t)(aofs[j] + kb),
                         ldsA + buf * 32768 + (j * 8 + w) * 1024);
    };
    auto stageB = [&](int kt, int buf) {
        const uint32_t kb = (uint32_t)kt << 7;
        #pragma unroll
        for (int j = 0; j < JB; j++)
            if (j * 8 + w < BSUB)
                async_load16((const char*)Bm + (size_t)(bofs[j] + kb),
                             ldsB + buf * BBY + (j * 8 + w) * 1024);
    };

    const int nkt = K >> 6;            // 48
    stageB(0, 0); stageA(0, 0);
    stageB(1, 1); stageA(1, 1);

    for (int t = 0; t < nkt; t++) {
        const int c = t & 1;
        const char* ab = ldsA + c * 32768 + aoff;
        const char* bb = ldsB + c * BBY + boff;

        if (BN == 288) asm volatile("s_waitcnt vmcnt(8)" ::: "memory");
        else           asm volatile("s_waitcnt vmcnt(7)" ::: "memory");
        __builtin_amdgcn_s_barrier();
        __builtin_amdgcn_sched_barrier(0);             // no read hoists above the barrier

        short8 a[4][2], bring[3][2];
        #pragma unroll
        for (int i = 0; i < 4; i++)
            #pragma unroll
            for (int kk = 0; kk < 2; kk++)
                a[i][kk] = *(const short8*)(ab + i * 2048 + kk * 1024);
        #pragma unroll
        for (int kk = 0; kk < 2; kk++)
            bring[0][kk] = *(const short8*)(bb + kk * 1024);

        // phases 0..NF-2: prefetch frag g+1 into ring slot (g+1)%3, MFMA frag g
        #pragma unroll
        for (int g = 0; g < NF - 1; g++) {
            #pragma unroll
            for (int kk = 0; kk < 2; kk++)
                bring[(g + 1) % 3][kk] = *(const short8*)(bb + (g + 1) * 2048 + kk * 1024);
            __builtin_amdgcn_s_setprio(1);
            #pragma unroll
            for (int kk = 0; kk < 2; kk++)
                #pragma unroll
                for (int i = 0; i < 4; i++)
                    acc[i][g] = __builtin_amdgcn_mfma_f32_16x16x32_bf16(a[i][kk], bring[g % 3][kk], acc[i][g], 0, 0, 0);
            __builtin_amdgcn_s_setprio(0);
        }
        // all buf-c reads issued; stage t+2 into buf c, overlap with final MFMA phase
        __builtin_amdgcn_sched_barrier(0);
        __builtin_amdgcn_s_barrier();
        __builtin_amdgcn_sched_barrier(0);
        if (t + 2 < nkt) { stageB(t + 2, c); stageA(t + 2, c); }
        __builtin_amdgcn_s_setprio(1);
        #pragma unroll
        for (int kk = 0; kk < 2; kk++)
            #pragma unroll
            for (int i = 0; i < 4; i++)
                acc[i][NF - 1] = __builtin_amdgcn_mfma_f32_16x16x32_bf16(a[i][kk], bring[(NF - 1) % 3][kk], acc[i][NF - 1], 0, 0, 0);
        __builtin_amdgcn_s_setprio(0);
    }
    asm volatile("s_waitcnt vmcnt(0)" ::: "memory");

    // C/D layout: col = lane&15, row = quad*4 + reg
    #pragma unroll
    for (int i = 0; i < 4; i++)
        #pragma unroll
        for (int j = 0; j < NF; j++)
            #pragma unroll
            for (int r = 0; r < 4; r++) {
                const int row = m0 + wr * 64 + i * 16 + quad * 4 + r;
                const int col = n0 + wc * (BN / 2) + j * 16 + L15;
                const float v = acc[i][j][r];
                if (OUT_BF16) Cb[(size_t)row * N + col] = f2bf(v);
                else          Cf[(size_t)row * N + col] = v;
            }
}

// ---------------------------------------------------------------- RoPE cos/sin table
// Only B*S*48 distinct (cos,sin) pairs exist; precompute once (pure VALU, tiny)
// so rope_reorder becomes a memory-bound pass (15.7M sincos+exp2 -> 196K).
#define TABN (B_ * S_ * 48)
__global__ void rope_tab(const int* __restrict__ pos_ids, float2* __restrict__ tab) {
    int i = blockIdx.x * blockDim.x + threadIdx.x;
    if (i >= TABN) return;
    int fi = i % 48, sb = i / 48;
    float inv = exp2f((float)fi * -0.2768273412f);   // 10000^(-fi/48)
    float theta = (float)pos_ids[sb] * inv;
    float sn, cs;
    __sincosf(theta, &sn, &cs);
    tab[i] = make_float2(cs, sn);
}

// ---------------------------------------------------------------- RoPE + reorder q,k
// Q gets (1/sqrt(96))*log2(e) folded in (flash softmax uses exp2).
// K written into PADDED+ROTATED tile layout: Kc[(b*NKV+kvh)*S + s][chunk(16)][8]
// with phys_chunk = (logical_chunk + s) & 15 -> bank-conflict-free LDS image.
__global__ void rope_reorder(const short* __restrict__ qkv, const float2* __restrict__ tab,
                             short* __restrict__ Q, short* __restrict__ Kc) {
    const int total = B_ * S_ * (NH + NKV) * HD;
    int idx = blockIdx.x * blockDim.x + threadIdx.x;
    int stride = gridDim.x * blockDim.x;
    for (; idx < total; idx += stride) {
        int d = idx % HD;
        int row = idx / HD;
        int h_all = row % (NH + NKV);
        int sb = row / (NH + NKV);          // = b*S_+s
        int s = sb % S_;
        int b = sb / S_;
        int base = sb * OPSZ;
        int off = (h_all < NH) ? (h_all * HD + d) : (H_ + (h_all - NH) * HD + d);
        float x = bf2f(qkv[base + off]);
        int delta = (d < 48) ? 48 : -48;
        float x2 = bf2f(qkv[base + off + delta]);
        int fi = d % 48;
        float2 t = tab[sb * 48 + fi];
        float rot = (d < 48) ? -x2 : x2;
        float outv = x * t.x + rot * t.y;
        if (h_all < NH) {
            outv *= 0.14724438747f; // (1/sqrt(96)) * log2(e)
            Q[((size_t)(b * NH + h_all) * S_ + s) * HD + d] = f2bf(outv);
        } else {
            int kvh = h_all - NH;
            size_t kaddr = ((size_t)(b * NKV + kvh) * S_ + s) * 128
                         + (((d >> 3) + s) & 15) * 8 + (d & 7);
            Kc[kaddr] = f2bf(outv);
        }
    }
}

// ---------------------------------------------------------------- V transpose + swizzle (verified)
__global__ __launch_bounds__(256) void v_transpose(const short* __restrict__ qkv, short* __restrict__ Vt) {
    __shared__ short tile[64 * 104];
    int blk = blockIdx.x;
    int st  = blk & 31;
    int kvh = (blk >> 5) & 7;
    int b   = blk >> 8;
    int s0  = st * 64;
    int tid = threadIdx.x;
    #pragma unroll
    for (int i = 0; i < 3; i++) {
        int c = tid + i * 256;               // 64 rows x 12 chunks
        int row = c / 12, col8 = c % 12;
        *(short8*)&tile[row * 104 + col8 * 8] =
            *(const short8*)(qkv + (size_t)(b * S_ + s0 + row) * OPSZ + 3840 + kvh * HD + col8 * 8);
    }
    __syncthreads();
    #pragma unroll
    for (int i = 0; i < 3; i++) {
        int c = tid + i * 256;               // 96 rows x 8 chunks
        int d = c >> 3, col8 = c & 7;
        int chunk0 = (col8 - d) & 7;         // inverse rotation
        short8 v;
        #pragma unroll
        for (int j = 0; j < 8; j++) {
            int col0 = chunk0 * 8 + j;       // perm-space column
            int n = ((col0 >> 5) << 1) | (col0 & 1);
            int t = (col0 & 31) >> 1;
            v[j] = tile[(n * 16 + t) * 104 + d];
        }
        *(short8*)(Vt + ((size_t)(b * NKV + kvh) * HD + d) * S_ + s0 + col8 * 8) = v;
    }
}

// ---------------------------------------------------------------- causal flash attention v4
// (exact round-2/4 verified 125.3-us version; round-6 wave-skip reverted: it cost
//  +4 VGPR and +2.4 us. Structure is at its local ceiling -- VALU/trans-pipe-bound
//  at 2 blocks/CU; defer-max (rounds 3,5) and wave-skip (round 6) both refuted.)
__global__ __launch_bounds__(256) void flash_attn(const short* __restrict__ Q, const short* __restrict__ Kc,
                                                  const short* __restrict__ Vt, short* __restrict__ attn) {
    __shared__ short kl[2][64 * 128];    // 32 KB  (padded+rotated DMA image)
    __shared__ short vl[2][112 * 64];    // 28 KB  (rows 96..111: ones-column block, constant)
    __shared__ short pl[4][32 * 72];     // 18.4 KB wave-private P
    const int x = blockIdx.x, h = blockIdx.y, b = blockIdx.z;
    const int kvh = h >> 2;
    const int tid = threadIdx.x, wave = tid >> 6, lane = tid & 63;
    const int L15 = lane & 15, quad = lane >> 4;

    #pragma unroll
    for (int i = 0; i < 2; i++) {
        uint32_t* p = (uint32_t*)&vl[i][96 * 64];
        #pragma unroll
        for (int k = 0; k < 2; k++) {
            int idx = tid + k * 256;
            p[idx] = (idx < 32) ? 0x3F803F80u : 0u;
        }
    }

    const short* kbase = Kc + (size_t)(b * NKV + kvh) * S_ * 128;
    const short* vbase = Vt + (size_t)(b * NKV + kvh) * HD * S_;
    const int klane   = lane * 8;
    const int vrow_lo = lane >> 3;
    const int vcol    = (lane & 7) * 8;

    int rotK[3], rotV[2];
    #pragma unroll
    for (int kk = 0; kk < 3; kk++) rotK[kk] = ((kk * 4 + quad + L15) & 15) * 8;
    #pragma unroll
    for (int kk = 0; kk < 2; kk++) rotV[kk] = ((kk * 4 + quad + L15) & 7) * 8;

    auto stage = [&](int kv0, int buf) {
        const short* ksrc = kbase + (size_t)kv0 * 128;
        #pragma unroll
        for (int i = 0; i < 4; i++) {
            int ck = wave * 4 + i;
            async_load16(ksrc + ck * 512 + klane, &kl[buf][ck * 512]);
        }
        #pragma unroll
        for (int i = 0; i < 3; i++) {
            int ck = wave * 3 + i;
            async_load16(vbase + (size_t)(ck * 8 + vrow_lo) * S_ + kv0 + vcol, &vl[buf][ck * 512]);
        }
    };

    #pragma unroll
    for (int pp = 0; pp < 2; pp++) {
        const int qt = pp ? x : (15 - x);
        const int q0 = qt * 128;
        const int jmax = 2 * qt + 2;

        short8 qf[2][3];
        #pragma unroll
        for (int mm = 0; mm < 2; mm++) {
            const short* qrow = Q + ((size_t)(b * NH + h) * S_ + q0 + wave * 32 + mm * 16 + L15) * HD;
            #pragma unroll
            for (int kk = 0; kk < 3; kk++) qf[mm][kk] = *(const short8*)(qrow + kk * 32 + quad * 8);
        }
        floatx4 o[2][7];                    // col 6 = row-sum accumulator (l)
        float m_r[2][4];
        #pragma unroll
        for (int mm = 0; mm < 2; mm++) {
            #pragma unroll
            for (int nn = 0; nn < 7; nn++) o[mm][nn] = (floatx4){0.f, 0.f, 0.f, 0.f};
            #pragma unroll
            for (int r = 0; r < 4; r++) m_r[mm][r] = -3.0e38f;
        }

        __syncthreads();
        stage(0, 0);

        for (int j = 0; j < jmax; j++) {
            const int c = j & 1;
            const int kv0 = j * 64;
            __syncthreads();
            if (j + 1 < jmax) stage(kv0 + 64, 1 - c);

            const short* klp = kl[c];
            const short* vlp = vl[c];

            floatx4 sacc[2][4];
            #pragma unroll
            for (int mm = 0; mm < 2; mm++)
                #pragma unroll
                for (int n = 0; n < 4; n++) sacc[mm][n] = (floatx4){0.f, 0.f, 0.f, 0.f};
            #pragma unroll
            for (int n = 0; n < 4; n++)
                #pragma unroll
                for (int kk = 0; kk < 3; kk++) {
                    short8 kf = *(const short8*)&klp[(n * 16 + L15) * 128 + rotK[kk]];
                    sacc[0][n] = __builtin_amdgcn_mfma_f32_16x16x32_bf16(qf[0][kk], kf, sacc[0][n], 0, 0, 0);
                    sacc[1][n] = __builtin_amdgcn_mfma_f32_16x16x32_bf16(qf[1][kk], kf, sacc[1][n], 0, 0, 0);
                }

            #pragma unroll
            for (int mm = 0; mm < 2; mm++) {
                const int tbase = q0 + wave * 32 + mm * 16;
                if (kv0 + 63 > tbase) {
                    int qr_base = tbase + quad * 4;
                    #pragma unroll
                    for (int n = 0; n < 4; n++) {
                        int kv = kv0 + n * 16 + L15;
                        #pragma unroll
                        for (int r = 0; r < 4; r++)
                            if (kv > qr_base + r) sacc[mm][n][r] = -3.0e38f;
                    }
                }
                float alpha[4];
                #pragma unroll
                for (int r = 0; r < 4; r++) {
                    float mx = fmaxf(fmaxf(sacc[mm][0][r], sacc[mm][1][r]),
                                     fmaxf(sacc[mm][2][r], sacc[mm][3][r]));
                    mx = dpp_max16(mx);
                    float mn = fmaxf(m_r[mm][r], mx);
                    alpha[r] = fast_exp2(m_r[mm][r] - mn);
                    m_r[mm][r] = mn;
                }
                #pragma unroll
                for (int n = 0; n < 4; n++)
                    #pragma unroll
                    for (int r = 0; r < 4; r++)
                        sacc[mm][n][r] = fast_exp2(sacc[mm][n][r] - m_r[mm][r]);
                #pragma unroll
                for (int r = 0; r < 4; r++) {
                    int prow = mm * 16 + quad * 4 + r;
                    *(uint32_t*)&pl[wave][prow * 72 + 2 * L15]      = pk_bf_trunc(sacc[mm][0][r], sacc[mm][1][r]);
                    *(uint32_t*)&pl[wave][prow * 72 + 32 + 2 * L15] = pk_bf_trunc(sacc[mm][2][r], sacc[mm][3][r]);
                }
                #pragma unroll
                for (int nn = 0; nn < 7; nn++)
                    #pragma unroll
                    for (int r = 0; r < 4; r++) o[mm][nn][r] *= alpha[r];
            }

            #pragma unroll
            for (int kk = 0; kk < 2; kk++) {
                short8 af0 = *(const short8*)&pl[wave][L15 * 72 + kk * 32 + quad * 8];
                short8 af1 = *(const short8*)&pl[wave][(16 + L15) * 72 + kk * 32 + quad * 8];
                #pragma unroll
                for (int nn = 0; nn < 7; nn++) {
                    short8 vf = *(const short8*)&vlp[(nn * 16 + L15) * 64 + rotV[kk]];
                    o[0][nn] = __builtin_amdgcn_mfma_f32_16x16x32_bf16(af0, vf, o[0][nn], 0, 0, 0);
                    o[1][nn] = __builtin_amdgcn_mfma_f32_16x16x32_bf16(af1, vf, o[1][nn], 0, 0, 0);
                }
            }
        }

        #pragma unroll
        for (int mm = 0; mm < 2; mm++) {
            float inv_l[4];
            #pragma unroll
            for (int r = 0; r < 4; r++) {
                float l = __shfl(o[mm][6][r], lane & 48);   // col 96 lives in L15==0
                inv_l[r] = 1.0f / l;
            }
            #pragma unroll
            for (int nn = 0; nn < 6; nn++)
                #pragma unroll
                for (int r = 0; r < 4; r++) {
                    float v = o[mm][nn][r] * inv_l[r];
                    int row = q0 + wave * 32 + mm * 16 + quad * 4 + r;
                    attn[((size_t)(b * S_) + row) * H_ + h * HD + nn * 16 + L15] = f2bf(v);
                }
        }
    }
}

// ---------------------------------------------------------------- launch
extern "C" void kernel_launch(void* const* d_in, const int* in_sizes, int n_in,
                              void* d_out, int out_size, void* d_ws, size_t ws_size,
                              hipStream_t stream) {
    const float* hid  = (const float*)d_in[0];
    const int*   pos  = (const int*)d_in[1];
    const float* wqkv = (const float*)d_in[2];
    const float* wo   = (const float*)d_in[3];
    float* out = (float*)d_out;
    char* ws = (char*)d_ws;

    short* hid_b  = (short*)(ws + 0L);          // 4096*3072 bf16 (later overlaid by tab/attn_b)
    short* wqkv_b = (short*)(ws + 25165824L);   // 4608*3072 bf16
    short* wo_b   = (short*)(ws + 53477376L);   // 3072*3072 bf16
    short* qkv_b  = (short*)(ws + 72351744L);   // 4096*4608 bf16
    short* q_b    = (short*)(ws + 110100480L);  // [B,NH,S,HD] bf16
    short* k_b    = (short*)(ws + 135266304L);  // [B,NKV,S,128] bf16 padded+rotated (8.39MB)
    short* vt_b   = (short*)(ws + 143654912L);  // [B,NKV,HD,S] bf16 (swizzled, 6.29MB)
    float2* tab   = (float2*)(ws + 0L);         // 1.57MB, overlays hid_b (dead after QKV GEMM)
    short* attn_b = (short*)(ws + 0L);          // overlays tab (dead after rope_reorder)

    cast3_f32_bf16<<<4096, 256, 0, stream>>>(hid, wqkv, wo, hid_b, wqkv_b, wo_b);

    // QKV: N=4608 = 16 tiles of 288; M=4096 = 16 tiles of 256 -> 256 blocks, 1 round
    gemmN<288, 1><<<256, 512, 0, stream>>>(hid_b, wqkv_b, nullptr, qkv_b, MM, OPSZ, H_);

    rope_tab<<<(TABN + 255) / 256, 256, 0, stream>>>((const int*)d_in[1], tab);
    rope_reorder<<<8192, 256, 0, stream>>>(qkv_b, tab, q_b, k_b);
    v_transpose<<<512, 256, 0, stream>>>(qkv_b, vt_b);

    flash_attn<<<dim3(8, NH, B_), 256, 0, stream>>>(q_b, k_b, vt_b, attn_b);

    // WO: N=3072 = 16 tiles of 192; M=4096 = 16 tiles of 256 -> 256 blocks, 1 round
    gemmN<192, 0><<<256, 512, 0, stream>>>(attn_b, wo_b, out, nullptr, MM, H_, H_);
}

// Round 8
// 462.392 us; speedup vs baseline: 1.0383x; 1.0383x over previous
//
#include <hip/hip_runtime.h>
#include <stdint.h>
#include <math.h>

// Problem constants (Phi3 attention block)
#define B_   2
#define S_   2048
#define H_   3072
#define NH   32
#define NKV  8
#define HD   96
#define OPSZ 4608          // NH*HD + 2*NKV*HD
#define MM   (B_*S_)       // 4096 token rows

typedef __attribute__((ext_vector_type(8))) short short8;
typedef __attribute__((ext_vector_type(4))) float floatx4;

__device__ __forceinline__ short f2bf(float f) {
    union { float f; uint32_t u; } v; v.f = f;
    uint32_t r = v.u + 0x7fffu + ((v.u >> 16) & 1u);   // RNE
    return (short)(r >> 16);
}
__device__ __forceinline__ float bf2f(short s) {
    union { uint32_t u; float f; } v; v.u = ((uint32_t)(uint16_t)s) << 16;
    return v.f;
}
// truncating bf16x2 pack (P in [0,1]; bias <= 2^-9 rel, numerator & denominator consistent)
__device__ __forceinline__ uint32_t pk_bf_trunc(float lo, float hi) {
    union { float f; uint32_t u; } a, b; a.f = lo; b.f = hi;
    return (a.u >> 16) | (b.u & 0xFFFF0000u);
}
// raw v_exp_f32 (base-2): skips OCML denorm-fixup tail; -3e38 input -> 0
__device__ __forceinline__ float fast_exp2(float x) {
    float r;
    asm volatile("v_exp_f32 %0, %1" : "=v"(r) : "v"(x));
    return r;
}
// max over the 16 lanes of a DPP row via row_ror rotate-reduce (pure VALU)
__device__ __forceinline__ float dpp_max16(float x) {
    union { float f; int i; } a, t;
    a.f = x;
    t.i = __builtin_amdgcn_update_dpp(0, a.i, 0x128, 0xF, 0xF, false); a.f = fmaxf(a.f, t.f);
    t.i = __builtin_amdgcn_update_dpp(0, a.i, 0x124, 0xF, 0xF, false); a.f = fmaxf(a.f, t.f);
    t.i = __builtin_amdgcn_update_dpp(0, a.i, 0x122, 0xF, 0xF, false); a.f = fmaxf(a.f, t.f);
    t.i = __builtin_amdgcn_update_dpp(0, a.i, 0x121, 0xF, 0xF, false); a.f = fmaxf(a.f, t.f);
    return a.f;
}

// async global->LDS, 16B per lane; lds dest is wave-uniform base + lane*16
__device__ __forceinline__ void async_load16(const void* g, void* l) {
    __builtin_amdgcn_global_load_lds(
        (const __attribute__((address_space(1))) void*)g,
        (__attribute__((address_space(3))) void*)l, 16, 0, 0);
}

// ---------------------------------------------------------------- merged casts fp32->bf16
#define CN1 (MM * H_ / 4)
#define CN2 (OPSZ * H_ / 4)
#define CN3 (H_ * H_ / 4)
__global__ void cast3_f32_bf16(const float* __restrict__ s1, const float* __restrict__ s2,
                               const float* __restrict__ s3, short* __restrict__ d1,
                               short* __restrict__ d2, short* __restrict__ d3) {
    int gid = blockIdx.x * blockDim.x + threadIdx.x;
    int stride = gridDim.x * blockDim.x;
    for (int i = gid; i < CN1; i += stride) {
        float4 v = ((const float4*)s1)[i];
        short4 o; o.x = f2bf(v.x); o.y = f2bf(v.y); o.z = f2bf(v.z); o.w = f2bf(v.w);
        ((short4*)d1)[i] = o;
    }
    for (int i = gid; i < CN2; i += stride) {
        float4 v = ((const float4*)s2)[i];
        short4 o; o.x = f2bf(v.x); o.y = f2bf(v.y); o.z = f2bf(v.z); o.w = f2bf(v.w);
        ((short4*)d2)[i] = o;
    }
    for (int i = gid; i < CN3; i += stride) {
        float4 v = ((const float4*)s3)[i];
        short4 o; o.x = f2bf(v.x); o.y = f2bf(v.y); o.z = f2bf(v.z); o.w = f2bf(v.w);
        ((short4*)d3)[i] = o;
    }
}

// ---------------------------------------------------------------- GEMM  C[M,N] = A[M,K] * B[N,K]^T
// v6 (kept from round 7, neutral-to-positive): BM=256, BN templated (288 QKV /
// 192 WO), 256 blocks, st_16x32 swizzle, counted vmcnt, 2 barriers/K-tile.
// K-loop: NF single-fragment phases with a 3-SLOT B ring (prefetch frag g+1 into
// slot (g+1)%3 while MFMA consumes slot g%3); peak live B regs 24.
template<int BN, int OUT_BF16>
__global__ __launch_bounds__(512, 2) void gemmN(const short* __restrict__ A, const short* __restrict__ Bm,
                                                float* __restrict__ Cf, short* __restrict__ Cb,
                                                int M, int N, int K) {
    constexpr int NF    = BN / 32;        // n-frags per wave (9 | 6)
    constexpr int BSUB  = BN / 8;         // B subtiles (36 | 24)
    constexpr int BBY   = BN * 128;       // B bytes per buffer
    constexpr int JB    = (BSUB + 7) / 8; // B stage loads upper bound per wave (5 | 3)
    __shared__ __align__(16) char smem[65536 + 2 * BBY];
    const int tid = threadIdx.x;
    const int w = tid >> 6, l = tid & 63;
    const int L15 = l & 15, quad = l >> 4;
    const int wr = w & 3, wc = w >> 2;    // wave grid 4x2

    const int gm = M >> 8;                // 16
    const int nwg = gridDim.x;
    const int id = blockIdx.x;
    // bijective XCD remap (m204)
    const int qq = nwg >> 3, rr = nwg & 7;
    const int xcd = id & 7, sidx = id >> 3;
    const int wgid = (xcd < rr ? xcd * (qq + 1) : rr * (qq + 1) + (xcd - rr) * qq) + sidx;
    const int m0 = (wgid % gm) << 8;
    const int n0 = (wgid / gm) * BN;

    // staging source byte-offsets (inverse st_16x32 swizzle folded into the source)
    const int cbl = ((l & 3) * 16) ^ (((l >> 5) & 1) << 5);
    uint32_t aofs[4], bofs[JB];
    #pragma unroll
    for (int j = 0; j < 4; j++) {
        const int s = j * 8 + w;
        const int row = ((s >> 1) << 4) + (l >> 2);
        const int colb = ((s & 1) << 6) + cbl;
        aofs[j] = (uint32_t)(m0 + row) * (uint32_t)(K * 2) + colb;
    }
    #pragma unroll
    for (int j = 0; j < JB; j++) {
        const int s = j * 8 + w;
        const int sc = (s < BSUB) ? s : 0;             // clamp (unused when guarded)
        const int row = ((sc >> 1) << 4) + (l >> 2);
        const int colb = ((sc & 1) << 6) + cbl;
        bofs[j] = (uint32_t)(n0 + row) * (uint32_t)(K * 2) + colb;
    }
    char* ldsA = (char*)smem;
    char* ldsB = (char*)smem + 65536;

    // ds_read lane constant: phys = subtile_pair*2048 + kk*1024 + L15*64 + (quad*16 ^ (L15bit3<<5))
    const int lane_off = L15 * 64 + ((quad * 16) ^ (((L15 >> 3) & 1) << 5));
    const int aoff = (wr * 4) * 2048 + lane_off;       // + m*2048 + kk*1024
    const int boff = (wc * NF) * 2048 + lane_off;      // + n*2048 + kk*1024

    floatx4 acc[4][NF];
    #pragma unroll
    for (int i = 0; i < 4; i++)
        #pragma unroll
        for (int j = 0; j < NF; j++)
            acc[i][j] = (floatx4){0.f, 0.f, 0.f, 0.f};

    auto stageA = [&](int kt, int buf) {
        const uint32_t kb = (uint32_t)kt << 7;
        #pragma unroll
        for (int j = 0; j < 4; j++)
            async_load16((const char*)A + (size_t)(aofs[j] + kb),
                         ldsA + buf * 32768 + (j * 8 + w) * 1024);
    };
    auto stageB = [&](int kt, int buf) {
        const uint32_t kb = (uint32_t)kt << 7;
        #pragma unroll
        for (int j = 0; j < JB; j++)
            if (j * 8 + w < BSUB)
                async_load16((const char*)Bm + (size_t)(bofs[j] + kb),
                             ldsB + buf * BBY + (j * 8 + w) * 1024);
    };

    const int nkt = K >> 6;            // 48
    stageB(0, 0); stageA(0, 0);
    stageB(1, 1); stageA(1, 1);

    for (int t = 0; t < nkt; t++) {
        const int c = t & 1;
        const char* ab = ldsA + c * 32768 + aoff;
        const char* bb = ldsB + c * BBY + boff;

        if (BN == 288) asm volatile("s_waitcnt vmcnt(8)" ::: "memory");
        else           asm volatile("s_waitcnt vmcnt(7)" ::: "memory");
        __builtin_amdgcn_s_barrier();
        __builtin_amdgcn_sched_barrier(0);             // no read hoists above the barrier

        short8 a[4][2], bring[3][2];
        #pragma unroll
        for (int i = 0; i < 4; i++)
            #pragma unroll
            for (int kk = 0; kk < 2; kk++)
                a[i][kk] = *(const short8*)(ab + i * 2048 + kk * 1024);
        #pragma unroll
        for (int kk = 0; kk < 2; kk++)
            bring[0][kk] = *(const short8*)(bb + kk * 1024);

        // phases 0..NF-2: prefetch frag g+1 into ring slot (g+1)%3, MFMA frag g
        #pragma unroll
        for (int g = 0; g < NF - 1; g++) {
            #pragma unroll
            for (int kk = 0; kk < 2; kk++)
                bring[(g + 1) % 3][kk] = *(const short8*)(bb + (g + 1) * 2048 + kk * 1024);
            __builtin_amdgcn_s_setprio(1);
            #pragma unroll
            for (int kk = 0; kk < 2; kk++)
                #pragma unroll
                for (int i = 0; i < 4; i++)
                    acc[i][g] = __builtin_amdgcn_mfma_f32_16x16x32_bf16(a[i][kk], bring[g % 3][kk], acc[i][g], 0, 0, 0);
            __builtin_amdgcn_s_setprio(0);
        }
        // all buf-c reads issued; stage t+2 into buf c, overlap with final MFMA phase
        __builtin_amdgcn_sched_barrier(0);
        __builtin_amdgcn_s_barrier();
        __builtin_amdgcn_sched_barrier(0);
        if (t + 2 < nkt) { stageB(t + 2, c); stageA(t + 2, c); }
        __builtin_amdgcn_s_setprio(1);
        #pragma unroll
        for (int kk = 0; kk < 2; kk++)
            #pragma unroll
            for (int i = 0; i < 4; i++)
                acc[i][NF - 1] = __builtin_amdgcn_mfma_f32_16x16x32_bf16(a[i][kk], bring[(NF - 1) % 3][kk], acc[i][NF - 1], 0, 0, 0);
        __builtin_amdgcn_s_setprio(0);
    }
    asm volatile("s_waitcnt vmcnt(0)" ::: "memory");

    // C/D layout: col = lane&15, row = quad*4 + reg
    #pragma unroll
    for (int i = 0; i < 4; i++)
        #pragma unroll
        for (int j = 0; j < NF; j++)
            #pragma unroll
            for (int r = 0; r < 4; r++) {
                const int row = m0 + wr * 64 + i * 16 + quad * 4 + r;
                const int col = n0 + wc * (BN / 2) + j * 16 + L15;
                const float v = acc[i][j][r];
                if (OUT_BF16) Cb[(size_t)row * N + col] = f2bf(v);
                else          Cf[(size_t)row * N + col] = v;
            }
}

// ---------------------------------------------------------------- fused RoPE + reorder + V transpose
// Replaces rope_tab + rope_reorder + v_transpose (3 launches -> 1) and deletes the
// global cos/sin table round-trip.
// Blocks 0..4095: one block per token (b,s). 48 (cos,sin) pairs computed into LDS
// (48 sincos/block), then RoPE applied pairwise: thread handles (d, d+48) with one
// tab entry -> out1 = x1*c - x2*s, out2 = x2*c + x1*s (IEEE-identical to the
// rotate-half formula; negation is exact).
//   Q gets (1/sqrt(96))*log2(e) folded in. K written into the padded+rotated
//   layout Kc[(b*NKV+kvh)*S+s][chunk(16)][8], phys_chunk=(logical+s)&15.
// Blocks 4096..4607: the verified v_transpose body (blk-4096), unchanged.
__global__ __launch_bounds__(256) void rope_vt(const short* __restrict__ qkv, const int* __restrict__ pos_ids,
                                               short* __restrict__ Q, short* __restrict__ Kc,
                                               short* __restrict__ Vt) {
    const int blk = blockIdx.x;
    const int tid = threadIdx.x;
    if (blk < B_ * S_) {
        __shared__ float2 ltab[48];
        const int s = blk % S_, b = blk / S_;
        if (tid < 48) {
            float inv = exp2f((float)tid * -0.2768273412f);   // 10000^(-fi/48)
            float theta = (float)pos_ids[blk] * inv;
            float sn, cs;
            __sincosf(theta, &sn, &cs);
            ltab[tid] = make_float2(cs, sn);
        }
        __syncthreads();
        const short* row = qkv + (size_t)blk * OPSZ;
        #pragma unroll 2
        for (int i = tid; i < (NH + NKV) * 48; i += 256) {
            const int h_all = i / 48, fi = i % 48;
            const int off = (h_all < NH) ? (h_all * HD + fi) : (H_ + (h_all - NH) * HD + fi);
            float x1 = bf2f(row[off]);
            float x2 = bf2f(row[off + 48]);
            float2 t = ltab[fi];
            float o1 = x1 * t.x - x2 * t.y;
            float o2 = x2 * t.x + x1 * t.y;
            if (h_all < NH) {
                o1 *= 0.14724438747f;                          // (1/sqrt(96)) * log2(e)
                o2 *= 0.14724438747f;
                size_t qa = ((size_t)(b * NH + h_all) * S_ + s) * HD + fi;
                Q[qa]      = f2bf(o1);
                Q[qa + 48] = f2bf(o2);
            } else {
                const int kvh = h_all - NH;
                size_t kb_ = ((size_t)(b * NKV + kvh) * S_ + s) * 128;
                const int d2 = fi + 48;
                Kc[kb_ + (((fi >> 3) + s) & 15) * 8 + (fi & 7)] = f2bf(o1);
                Kc[kb_ + (((d2 >> 3) + s) & 15) * 8 + (d2 & 7)] = f2bf(o2);
            }
        }
    } else {
        __shared__ short tile[64 * 104];
        const int vblk = blk - B_ * S_;
        const int st  = vblk & 31;
        const int kvh = (vblk >> 5) & 7;
        const int b   = vblk >> 8;
        const int s0  = st * 64;
        #pragma unroll
        for (int i = 0; i < 3; i++) {
            int c = tid + i * 256;               // 64 rows x 12 chunks
            int row = c / 12, col8 = c % 12;
            *(short8*)&tile[row * 104 + col8 * 8] =
                *(const short8*)(qkv + (size_t)(b * S_ + s0 + row) * OPSZ + 3840 + kvh * HD + col8 * 8);
        }
        __syncthreads();
        #pragma unroll
        for (int i = 0; i < 3; i++) {
            int c = tid + i * 256;               // 96 rows x 8 chunks
            int d = c >> 3, col8 = c & 7;
            int chunk0 = (col8 - d) & 7;         // inverse rotation
            short8 v;
            #pragma unroll
            for (int j = 0; j < 8; j++) {
                int col0 = chunk0 * 8 + j;       // perm-space column
                int n = ((col0 >> 5) << 1) | (col0 & 1);
                int t = (col0 & 31) >> 1;
                v[j] = tile[(n * 16 + t) * 104 + d];
            }
            *(short8*)(Vt + ((size_t)(b * NKV + kvh) * HD + d) * S_ + s0 + col8 * 8) = v;
        }
    }
}

// ---------------------------------------------------------------- causal flash attention v4
// (exact verified 125-us version; at its local structural ceiling -- defer-max
//  (rounds 3,5) and wave-skip (round 6) both refuted; VGPR must stay <= 124/128.)
__global__ __launch_bounds__(256) void flash_attn(const short* __restrict__ Q, const short* __restrict__ Kc,
                                                  const short* __restrict__ Vt, short* __restrict__ attn) {
    __shared__ short kl[2][64 * 128];    // 32 KB  (padded+rotated DMA image)
    __shared__ short vl[2][112 * 64];    // 28 KB  (rows 96..111: ones-column block, constant)
    __shared__ short pl[4][32 * 72];     // 18.4 KB wave-private P
    const int x = blockIdx.x, h = blockIdx.y, b = blockIdx.z;
    const int kvh = h >> 2;
    const int tid = threadIdx.x, wave = tid >> 6, lane = tid & 63;
    const int L15 = lane & 15, quad = lane >> 4;

    #pragma unroll
    for (int i = 0; i < 2; i++) {
        uint32_t* p = (uint32_t*)&vl[i][96 * 64];
        #pragma unroll
        for (int k = 0; k < 2; k++) {
            int idx = tid + k * 256;
            p[idx] = (idx < 32) ? 0x3F803F80u : 0u;
        }
    }

    const short* kbase = Kc + (size_t)(b * NKV + kvh) * S_ * 128;
    const short* vbase = Vt + (size_t)(b * NKV + kvh) * HD * S_;
    const int klane   = lane * 8;
    const int vrow_lo = lane >> 3;
    const int vcol    = (lane & 7) * 8;

    int rotK[3], rotV[2];
    #pragma unroll
    for (int kk = 0; kk < 3; kk++) rotK[kk] = ((kk * 4 + quad + L15) & 15) * 8;
    #pragma unroll
    for (int kk = 0; kk < 2; kk++) rotV[kk] = ((kk * 4 + quad + L15) & 7) * 8;

    auto stage = [&](int kv0, int buf) {
        const short* ksrc = kbase + (size_t)kv0 * 128;
        #pragma unroll
        for (int i = 0; i < 4; i++) {
            int ck = wave * 4 + i;
            async_load16(ksrc + ck * 512 + klane, &kl[buf][ck * 512]);
        }
        #pragma unroll
        for (int i = 0; i < 3; i++) {
            int ck = wave * 3 + i;
            async_load16(vbase + (size_t)(ck * 8 + vrow_lo) * S_ + kv0 + vcol, &vl[buf][ck * 512]);
        }
    };

    #pragma unroll
    for (int pp = 0; pp < 2; pp++) {
        const int qt = pp ? x : (15 - x);
        const int q0 = qt * 128;
        const int jmax = 2 * qt + 2;

        short8 qf[2][3];
        #pragma unroll
        for (int mm = 0; mm < 2; mm++) {
            const short* qrow = Q + ((size_t)(b * NH + h) * S_ + q0 + wave * 32 + mm * 16 + L15) * HD;
            #pragma unroll
            for (int kk = 0; kk < 3; kk++) qf[mm][kk] = *(const short8*)(qrow + kk * 32 + quad * 8);
        }
        floatx4 o[2][7];                    // col 6 = row-sum accumulator (l)
        float m_r[2][4];
        #pragma unroll
        for (int mm = 0; mm < 2; mm++) {
            #pragma unroll
            for (int nn = 0; nn < 7; nn++) o[mm][nn] = (floatx4){0.f, 0.f, 0.f, 0.f};
            #pragma unroll
            for (int r = 0; r < 4; r++) m_r[mm][r] = -3.0e38f;
        }

        __syncthreads();
        stage(0, 0);

        for (int j = 0; j < jmax; j++) {
            const int c = j & 1;
            const int kv0 = j * 64;
            __syncthreads();
            if (j + 1 < jmax) stage(kv0 + 64, 1 - c);

            const short* klp = kl[c];
            const short* vlp = vl[c];

            floatx4 sacc[2][4];
            #pragma unroll
            for (int mm = 0; mm < 2; mm++)
                #pragma unroll
                for (int n = 0; n < 4; n++) sacc[mm][n] = (floatx4){0.f, 0.f, 0.f, 0.f};
            #pragma unroll
            for (int n = 0; n < 4; n++)
                #pragma unroll
                for (int kk = 0; kk < 3; kk++) {
                    short8 kf = *(const short8*)&klp[(n * 16 + L15) * 128 + rotK[kk]];
                    sacc[0][n] = __builtin_amdgcn_mfma_f32_16x16x32_bf16(qf[0][kk], kf, sacc[0][n], 0, 0, 0);
                    sacc[1][n] = __builtin_amdgcn_mfma_f32_16x16x32_bf16(qf[1][kk], kf, sacc[1][n], 0, 0, 0);
                }

            #pragma unroll
            for (int mm = 0; mm < 2; mm++) {
                const int tbase = q0 + wave * 32 + mm * 16;
                if (kv0 + 63 > tbase) {
                    int qr_base = tbase + quad * 4;
                    #pragma unroll
                    for (int n = 0; n < 4; n++) {
                        int kv = kv0 + n * 16 + L15;
                        #pragma unroll
                        for (int r = 0; r < 4; r++)
                            if (kv > qr_base + r) sacc[mm][n][r] = -3.0e38f;
                    }
                }
                float alpha[4];
                #pragma unroll
                for (int r = 0; r < 4; r++) {
                    float mx = fmaxf(fmaxf(sacc[mm][0][r], sacc[mm][1][r]),
                                     fmaxf(sacc[mm][2][r], sacc[mm][3][r]));
                    mx = dpp_max16(mx);
                    float mn = fmaxf(m_r[mm][r], mx);
                    alpha[r] = fast_exp2(m_r[mm][r] - mn);
                    m_r[mm][r] = mn;
                }
                #pragma unroll
                for (int n = 0; n < 4; n++)
                    #pragma unroll
                    for (int r = 0; r < 4; r++)
                        sacc[mm][n][r] = fast_exp2(sacc[mm][n][r] - m_r[mm][r]);
                #pragma unroll
                for (int r = 0; r < 4; r++) {
                    int prow = mm * 16 + quad * 4 + r;
                    *(uint32_t*)&pl[wave][prow * 72 + 2 * L15]      = pk_bf_trunc(sacc[mm][0][r], sacc[mm][1][r]);
                    *(uint32_t*)&pl[wave][prow * 72 + 32 + 2 * L15] = pk_bf_trunc(sacc[mm][2][r], sacc[mm][3][r]);
                }
                #pragma unroll
                for (int nn = 0; nn < 7; nn++)
                    #pragma unroll
                    for (int r = 0; r < 4; r++) o[mm][nn][r] *= alpha[r];
            }

            #pragma unroll
            for (int kk = 0; kk < 2; kk++) {
                short8 af0 = *(const short8*)&pl[wave][L15 * 72 + kk * 32 + quad * 8];
                short8 af1 = *(const short8*)&pl[wave][(16 + L15) * 72 + kk * 32 + quad * 8];
                #pragma unroll
                for (int nn = 0; nn < 7; nn++) {
                    short8 vf = *(const short8*)&vlp[(nn * 16 + L15) * 64 + rotV[kk]];
                    o[0][nn] = __builtin_amdgcn_mfma_f32_16x16x32_bf16(af0, vf, o[0][nn], 0, 0, 0);
                    o[1][nn] = __builtin_amdgcn_mfma_f32_16x16x32_bf16(af1, vf, o[1][nn], 0, 0, 0);
                }
            }
        }

        #pragma unroll
        for (int mm = 0; mm < 2; mm++) {
            float inv_l[4];
            #pragma unroll
            for (int r = 0; r < 4; r++) {
                float l = __shfl(o[mm][6][r], lane & 48);   // col 96 lives in L15==0
                inv_l[r] = 1.0f / l;
            }
            #pragma unroll
            for (int nn = 0; nn < 6; nn++)
                #pragma unroll
                for (int r = 0; r < 4; r++) {
                    float v = o[mm][nn][r] * inv_l[r];
                    int row = q0 + wave * 32 + mm * 16 + quad * 4 + r;
                    attn[((size_t)(b * S_) + row) * H_ + h * HD + nn * 16 + L15] = f2bf(v);
                }
        }
    }
}

// ---------------------------------------------------------------- launch
extern "C" void kernel_launch(void* const* d_in, const int* in_sizes, int n_in,
                              void* d_out, int out_size, void* d_ws, size_t ws_size,
                              hipStream_t stream) {
    const float* hid  = (const float*)d_in[0];
    const int*   pos  = (const int*)d_in[1];
    const float* wqkv = (const float*)d_in[2];
    const float* wo   = (const float*)d_in[3];
    float* out = (float*)d_out;
    char* ws = (char*)d_ws;

    short* hid_b  = (short*)(ws + 0L);          // 4096*3072 bf16 (later overlaid by attn_b)
    short* wqkv_b = (short*)(ws + 25165824L);   // 4608*3072 bf16
    short* wo_b   = (short*)(ws + 53477376L);   // 3072*3072 bf16
    short* qkv_b  = (short*)(ws + 72351744L);   // 4096*4608 bf16
    short* q_b    = (short*)(ws + 110100480L);  // [B,NH,S,HD] bf16
    short* k_b    = (short*)(ws + 135266304L);  // [B,NKV,S,128] bf16 padded+rotated (8.39MB)
    short* vt_b   = (short*)(ws + 143654912L);  // [B,NKV,HD,S] bf16 (swizzled, 6.29MB)
    short* attn_b = (short*)(ws + 0L);          // overlays hid_b (hid dead after QKV GEMM)

    cast3_f32_bf16<<<4096, 256, 0, stream>>>(hid, wqkv, wo, hid_b, wqkv_b, wo_b);

    // QKV: N=4608 = 16 tiles of 288; M=4096 = 16 tiles of 256 -> 256 blocks, 1 round
    gemmN<288, 1><<<256, 512, 0, stream>>>(hid_b, wqkv_b, nullptr, qkv_b, MM, OPSZ, H_);

    // fused RoPE(+table-in-LDS) + K-reorder + V-transpose: blocks 0..4095 rope, 4096..4607 vt
    rope_vt<<<B_ * S_ + 512, 256, 0, stream>>>(qkv_b, pos, q_b, k_b, vt_b);

    flash_attn<<<dim3(8, NH, B_), 256, 0, stream>>>(q_b, k_b, vt_b, attn_b);

    // WO: N=3072 = 16 tiles of 192; M=4096 = 16 tiles of 256 -> 256 blocks, 1 round
    gemmN<192, 0><<<256, 512, 0, stream>>>(attn_b, wo_b, out, nullptr, MM, H_, H_);
}